// Round 12
// baseline (128.067 us; speedup 1.0000x reference)
//
#include <hip/hip_runtime.h>

#define NJ 24
#define NF 7
#define FS 6
#define SROW 37   // staging row stride in v4f units (36 data + 1 pad: breaks
                  // the 144-dword stride that put all even lanes on one bank)

typedef float v4f __attribute__((ext_vector_type(4)));

// parent of each joint; parents[i] < i, so sequential order is topological
__device__ constexpr int kParents[NJ] = {-1, 0, 0, 0, 1, 2, 3, 4, 5, 6, 7, 8,
                                          9, 9, 9, 12, 13, 14, 16, 17, 18, 19, 20, 21};

// Requires B % 64 == 0 (bench: B = 524288).
// Block = 128 threads: wave 0 computes + stages 64 samples; wave 1 is a
// dedicated writer that streams the block's 36 KB output as 36 sequential
// 1KB wave-stores (the fill kernel's access pattern, which sustains
// 6.9 TB/s at ~3 waves/CU). LDS 37.9 KB -> 4 blocks/CU; per CU 4 compute
// + 4 writer waves pipeline across blocks.
__global__ __launch_bounds__(128, 2) void se1d_kernel(
    const float* __restrict__ x,
    const float* __restrict__ W1,
    const float* __restrict__ b1,
    const float* __restrict__ W2,
    const float* __restrict__ b2,
    float* __restrict__ out, int B)
{
    __shared__ v4f sm[64 * SROW];   // 37888 B

    const int t    = threadIdx.x;
    const int lane = t & 63;
    const int wid  = t >> 6;            // 0 = compute wave, 1 = writer wave
    const int base = blockIdx.x * 64;   // this block's 64 samples

    if (wid == 0) {
        // ---------------- compute wave ----------------
        const int b = base + lane;

        // 24 x-values: 96 B contiguous, 16B-aligned.
        float xr[NJ];
        {
            const v4f* xv = reinterpret_cast<const v4f*>(x + (size_t)b * NJ);
            #pragma unroll
            for (int c = 0; c < NJ / 4; ++c) {
                v4f v = xv[c];
                xr[c * 4 + 0] = v.x; xr[c * 4 + 1] = v.y;
                xr[c * 4 + 2] = v.z; xr[c * 4 + 3] = v.w;
            }
        }

        // Weights: compile-time-constant indices off uniform kernel args ->
        // s_load into SGPRs, v_fmac consumes the SGPR operand (proven path).
        float feats[NJ][FS];   // fully unrolled -> registers, ~3 joints live
        v4f* const myStage = &sm[lane * SROW];

        #pragma unroll
        for (int i = 0; i < NJ; ++i) {
            const int p = kParents[i];

            float inp[NF];
            inp[0] = xr[i];
            #pragma unroll
            for (int j = 0; j < FS; ++j)
                inp[1 + j] = (p < 0) ? 0.0f : feats[p][j];

            float h[NF];
            #pragma unroll
            for (int j = 0; j < NF; ++j) h[j] = b1[i * NF + j];
            #pragma unroll
            for (int k = 0; k < NF; ++k) {
                const float a = inp[k];
                #pragma unroll
                for (int j = 0; j < NF; ++j)
                    h[j] = fmaf(a, W1[i * NF * NF + k * NF + j], h[j]);
            }
            #pragma unroll
            for (int j = 0; j < NF; ++j) h[j] = fmaxf(h[j], 0.0f);

            float f[FS];
            #pragma unroll
            for (int j = 0; j < FS; ++j) f[j] = b2[i * FS + j];
            #pragma unroll
            for (int k = 0; k < NF; ++k) {
                const float a = h[k];
                #pragma unroll
                for (int j = 0; j < FS; ++j)
                    f[j] = fmaf(a, W2[i * NF * FS + k * FS + j], f[j]);
            }
            #pragma unroll
            for (int j = 0; j < FS; ++j) {
                f[j] = fmaxf(f[j], 0.0f);
                feats[i][j] = f[j];
            }

            // Stage completed joint-pair: 3 v4f into this sample's LDS row
            // (row layout == output row layout, 36 v4f = 576 B).
            if (i & 1) {
                const int pp = i >> 1;            // 0..11
                v4f* st = myStage + pp * 3;
                st[0] = (v4f){feats[i - 1][0], feats[i - 1][1],
                              feats[i - 1][2], feats[i - 1][3]};
                st[1] = (v4f){feats[i - 1][4], feats[i - 1][5], f[0], f[1]};
                st[2] = (v4f){f[2], f[3], f[4], f[5]};
            }
        }
    }

    __syncthreads();   // staging complete -> writer may stream

    if (wid == 1) {
        // ---------------- writer wave ----------------
        // 36 sequential 1KB wave-stores covering the block's 36 KB output
        // region back-to-back (lane-contiguous, full 64B lines, page-local).
        v4f* const outv = reinterpret_cast<v4f*>(out) + (size_t)base * 36;
        #pragma unroll
        for (int j = 0; j < 36; ++j) {
            const int G = j * 64 + lane;       // global v4f index in region
            const int s = G / 36;              // sample row
            const int q = G - s * 36;          // v4f within row
            v4f v = sm[s * SROW + q];
            outv[G] = v;
        }
    }
    (void)B;
}

extern "C" void kernel_launch(void* const* d_in, const int* in_sizes, int n_in,
                              void* d_out, int out_size, void* d_ws, size_t ws_size,
                              hipStream_t stream) {
    const float* x  = (const float*)d_in[0];
    const float* W1 = (const float*)d_in[1];
    const float* b1 = (const float*)d_in[2];
    const float* W2 = (const float*)d_in[3];
    const float* b2 = (const float*)d_in[4];
    float* out = (float*)d_out;
    const int B = in_sizes[0] / NJ;   // 524288, multiple of 64
    const int grid = B / 64;
    hipLaunchKernelGGL(se1d_kernel, dim3(grid), dim3(128), 0, stream,
                       x, W1, b1, W2, b2, out, B);
}